// Round 1
// baseline (94.586 us; speedup 1.0000x reference)
//
#include <hip/hip_runtime.h>
#include <hip/hip_bf16.h>
#include <stdint.h>

// Problem constants (from reference spec)
static constexpr int P       = 24;    // residue pad length
static constexpr int EMB_D   = 32;    // ACD=ATD=RCD=RID=32
static constexpr int N_AC    = 38;
static constexpr int N_AT    = 6;
static constexpr int N_RC    = 21;
static constexpr int MAXSEQ  = 1024;
static constexpr int VEC_OUT = 64;
static constexpr int SC_OUT  = 256;
static constexpr int FEAT    = 3 * VEC_OUT + SC_OUT; // 448

__device__ __forceinline__ float b2f(unsigned short u) {
    return __uint_as_float(((uint32_t)u) << 16);
}
__device__ __forceinline__ unsigned short f2bf(float f) {
    uint32_t x = __float_as_uint(f);
    uint32_t r = (x + 0x7FFFu + ((x >> 16) & 1u)) >> 16;  // RNE
    return (unsigned short)r;
}

__global__ void init_bounds(int* __restrict__ starts, int* __restrict__ ends, int R) {
    int i = blockIdx.x * blockDim.x + threadIdx.x;
    if (i < R) { starts[i] = 0; ends[i] = 0; }
}

// residue_index_atomwise is sorted; detect run boundaries.
__global__ void find_bounds(const int* __restrict__ ri, int* __restrict__ starts,
                            int* __restrict__ ends, int N) {
    int i = blockIdx.x * blockDim.x + threadIdx.x;
    if (i >= N) return;
    int r = ri[i];
    if (i == 0 || ri[i - 1] != r) starts[r] = i;
    if (i == N - 1 || ri[i + 1] != r) ends[r] = i + 1;
}

// E[(p*n_emb + e)*256 + o] = scale * sum_d Wemb[e*32+d] * Wsc[(sc_base + p*32 + d)*256 + o]
__global__ __launch_bounds__(SC_OUT) void build_table(
        const float* __restrict__ Wemb, const float* __restrict__ Wsc,
        unsigned short* __restrict__ E, int n_emb, int sc_base, float scale) {
    int b = blockIdx.x;
    int p = b / n_emb;
    int e = b % n_emb;
    int o = threadIdx.x;
    const float* wrow = Wemb + (size_t)e * EMB_D;
    const float* scol = Wsc + (size_t)(sc_base + p * EMB_D) * SC_OUT + o;
    float s = 0.f;
#pragma unroll
    for (int d = 0; d < EMB_D; ++d) s += wrow[d] * scol[(size_t)d * SC_OUT];
    E[(size_t)b * SC_OUT + o] = f2bf(s * scale);
}

__global__ __launch_bounds__(256) void residue_kernel(
        const float* __restrict__ base, const float* __restrict__ rel,
        const int* __restrict__ rcode, const int* __restrict__ rseq,
        const int* __restrict__ acode, const int* __restrict__ atype,
        const int* __restrict__ starts, const int* __restrict__ ends,
        const unsigned short* __restrict__ Ecode, const unsigned short* __restrict__ Etype,
        const unsigned short* __restrict__ Erc, const unsigned short* __restrict__ Erix,
        const float* __restrict__ Wvec,
        float* __restrict__ out_coords, float* __restrict__ out_feat, int R) {
    int wid = (blockIdx.x * blockDim.x + threadIdx.x) >> 6;
    int lane = threadIdx.x & 63;
    if (wid >= R) return;
    const int r = wid;
    const int off = starts[r];
    int cnt = ends[r] - off;
    if (cnt > P) cnt = P;          // jnp scatter drops OOB positions
    // lanes 0..cnt-1 each preload one atom's data, broadcast via shfl
    int myc = 0, myt = 0;
    float mrx = 0.f, mry = 0.f, mrz = 0.f;
    if (lane < cnt) {
        int i = off + lane;
        myc = acode[i];
        myt = atype[i];
        mrx = rel[3 * (size_t)i];
        mry = rel[3 * (size_t)i + 1];
        mrz = rel[3 * (size_t)i + 2];
    }
    float a0 = 0.f, a1 = 0.f, a2 = 0.f, a3 = 0.f;   // sc outputs lane*4..+3
    float v0 = 0.f, v1 = 0.f, v2 = 0.f;             // vec output m = lane
    for (int j = 0; j < cnt; ++j) {
        int c = __shfl(myc, j);
        int t = __shfl(myt, j);
        float ax = __shfl(mrx, j);
        float ay = __shfl(mry, j);
        float az = __shfl(mrz, j);
        ushort4 ec = *reinterpret_cast<const ushort4*>(
            Ecode + ((size_t)(j * N_AC + c) * SC_OUT) + lane * 4);
        ushort4 et = *reinterpret_cast<const ushort4*>(
            Etype + ((size_t)(j * N_AT + t) * SC_OUT) + lane * 4);
        a0 += b2f(ec.x) + b2f(et.x);
        a1 += b2f(ec.y) + b2f(et.y);
        a2 += b2f(ec.z) + b2f(et.z);
        a3 += b2f(ec.w) + b2f(et.w);
        float w = Wvec[j * VEC_OUT + lane];
        v0 = fmaf(ax, w, v0);
        v1 = fmaf(ay, w, v1);
        v2 = fmaf(az, w, v2);
    }
    int rc = rcode[r];
    int sq = rseq[r];
    ushort4 e1 = *reinterpret_cast<const ushort4*>(Erc + (size_t)rc * SC_OUT + lane * 4);
    ushort4 e2 = *reinterpret_cast<const ushort4*>(Erix + (size_t)sq * SC_OUT + lane * 4);
    a0 += b2f(e1.x) + b2f(e2.x);
    a1 += b2f(e1.y) + b2f(e2.y);
    a2 += b2f(e1.z) + b2f(e2.z);
    a3 += b2f(e1.w) + b2f(e2.w);

    const float vs = 0.20412414523193150818f;  // 1/sqrt(24)
    float* frow = out_feat + (size_t)r * FEAT;
    frow[lane * 3 + 0] = v0 * vs;
    frow[lane * 3 + 1] = v1 * vs;
    frow[lane * 3 + 2] = v2 * vs;
    *reinterpret_cast<float4*>(frow + 3 * VEC_OUT + lane * 4) =
        make_float4(a0, a1, a2, a3);
    if (lane < 3) out_coords[(size_t)r * 3 + lane] = base[(size_t)r * 3 + lane];
}

extern "C" void kernel_launch(void* const* d_in, const int* in_sizes, int n_in,
                              void* d_out, int out_size, void* d_ws, size_t ws_size,
                              hipStream_t stream) {
    const float* base  = (const float*)d_in[0];
    const float* rel   = (const float*)d_in[1];
    const int*   rcode = (const int*)d_in[2];
    const int*   rseq  = (const int*)d_in[3];
    const int*   acode = (const int*)d_in[4];
    const int*   atype = (const int*)d_in[5];
    const int*   ri    = (const int*)d_in[6];
    const float* Wac   = (const float*)d_in[7];
    const float* Wat   = (const float*)d_in[8];
    const float* Wrc   = (const float*)d_in[9];
    const float* Wri   = (const float*)d_in[10];
    const float* Wv    = (const float*)d_in[11];
    const float* Wsc   = (const float*)d_in[12];

    const int R = in_sizes[0] / 3;
    const int N = in_sizes[6];

    float* out_coords = (float*)d_out;
    float* out_feat   = out_coords + (size_t)R * 3;

    // workspace layout (16B aligned blocks)
    char* ws = (char*)d_ws;
    size_t ofs = 0;
    int* starts = (int*)(ws + ofs); ofs += ((size_t)R * 4 + 15) & ~15ULL;
    int* ends   = (int*)(ws + ofs); ofs += ((size_t)R * 4 + 15) & ~15ULL;
    unsigned short* Ecode = (unsigned short*)(ws + ofs); ofs += (size_t)P * N_AC * SC_OUT * 2;
    unsigned short* Etype = (unsigned short*)(ws + ofs); ofs += (size_t)P * N_AT * SC_OUT * 2;
    unsigned short* Erc   = (unsigned short*)(ws + ofs); ofs += (size_t)N_RC * SC_OUT * 2;
    unsigned short* Erix  = (unsigned short*)(ws + ofs); ofs += (size_t)MAXSEQ * SC_OUT * 2;
    (void)ws_size; (void)n_in; (void)out_size;

    const float sc_scale = 0.025f;  // 1/sqrt(1600)

    init_bounds<<<(R + 255) / 256, 256, 0, stream>>>(starts, ends, R);
    find_bounds<<<(N + 255) / 256, 256, 0, stream>>>(ri, starts, ends, N);
    build_table<<<P * N_AC, SC_OUT, 0, stream>>>(Wac, Wsc, Ecode, N_AC, 0, sc_scale);
    build_table<<<P * N_AT, SC_OUT, 0, stream>>>(Wat, Wsc, Etype, N_AT, P * EMB_D, sc_scale);
    build_table<<<N_RC,     SC_OUT, 0, stream>>>(Wrc, Wsc, Erc, N_RC, 2 * P * EMB_D, sc_scale);
    build_table<<<MAXSEQ,   SC_OUT, 0, stream>>>(Wri, Wsc, Erix, MAXSEQ, 2 * P * EMB_D + EMB_D, sc_scale);

    residue_kernel<<<(R + 3) / 4, 256, 0, stream>>>(
        base, rel, rcode, rseq, acode, atype, starts, ends,
        Ecode, Etype, Erc, Erix, Wv, out_coords, out_feat, R);
}